// Round 7
// baseline (122.064 us; speedup 1.0000x reference)
//
#include <hip/hip_runtime.h>
#include <hip/hip_bf16.h>

// DiffRenderer v7: bf16-MFMA GEMM + COALESCED logits via global_load_lds.
// Round-6 post-mortem: removing lgkm drains was worth 2us -> stall is the
// softmax loads: 69 scalar dword loads/lane at 276B lane-stride = ~64 cache
// lines per instruction + L1 thrash (~2.6GB L2 line traffic). v7 stages each
// wave's 17664B logits chunk into LDS with 18 global_load_lds(16B) issues
// (linear, coalesced), one vmcnt(0), then lane reads its own row from LDS
// (2-way banks = free). Probs/a-frags/out-stage overlay the same wave-private
// LDS; no barriers anywhere. 1-wave blocks, 9 blocks/CU, grid = 2 full phases.
#define ROWS 384
#define COLS 768
#define NCH  69
#define CH   28
#define CW   14
#define KP   96             // K padded to 3 MFMA k-steps of 32
#define IMG_W 10752
#define ROW_U 104           // prob-row stride in ushorts (208B, 16B-aligned)
#define CHUNK_B (64 * NCH * 4)   // 17664 B: one wave's logits chunk

typedef __attribute__((ext_vector_type(8))) short bfrag;   // 8 bf16 (4 VGPR)
typedef __attribute__((ext_vector_type(4))) float f32x4;   // C/D frag

__device__ __forceinline__ unsigned bf16bits(float x) {
    unsigned b = __float_as_uint(x);
    b += 0x7FFFu + ((b >> 16) & 1u);   // RTNE
    return b >> 16;
}

__device__ __forceinline__ void gload_lds16(const void* g, void* l) {
    // HW: per-lane global src; LDS dest = wave-uniform base + lane*16
    __builtin_amdgcn_global_load_lds(
        (const __attribute__((address_space(1))) void*)g,
        (__attribute__((address_space(3))) void*)l, 16, 0, 0);
}

// ---- kernel 1: font (69,28,14) f32 -> Fh[28][16][96] bf16 ----
__global__ __launch_bounds__(256)
void font_prep(const float* __restrict__ font, unsigned short* __restrict__ Fh) {
    int idx = blockIdx.x * 256 + threadIdx.x;        // 28*16*96 = 43008
    if (idx >= CH * 16 * KP) return;
    int k  = idx % KP;
    int hw = idx / KP;
    int w  = hw % 16, h = hw / 16;
    float v = (w < CW && k < NCH) ? font[k * (CH * CW) + h * CW + w] : 0.f;
    Fh[idx] = (unsigned short)bf16bits(v);
}

// ---- kernel 2: softmax + MFMA blend + row-coalesced assemble ----
__global__ __launch_bounds__(64, 2)
void diffrender_v7(const float* __restrict__ logits,       // (294912,69) f32
                   const unsigned short* __restrict__ Fh,  // (28,16,96) bf16
                   float* __restrict__ out)                // (10752,10752) f32
{
    __shared__ __align__(16) unsigned char smem[CHUNK_B];  // 17664 B, wave-private

    const int lane = threadIdx.x;
    const int bid  = blockIdx.x;
    const int r    = bid / 12;                 // cell row (12 blocks/row)
    const int cb   = (bid % 12) * 64;          // first cell col of this block

    // ---- coalesced logits -> LDS, linear [64][69] f32 ----
    const char* gbase = (const char*)logits + (size_t)bid * CHUNK_B;
#pragma unroll
    for (int i = 0; i < 18; ++i) {
        const int off = (i < 17) ? i * 1024 : (CHUNK_B - 1024);  // tail overlaps
        gload_lds16(gbase + off + lane * 16, (void*)(smem + off));
    }
    asm volatile("s_waitcnt vmcnt(0)" ::: "memory");

    // ---- softmax from own LDS row (stride 69 dwords: 2-way banks, free) ----
    const float* myrow = (const float*)smem + (size_t)lane * NCH;
    float e[NCH];
    float m = -INFINITY;
#pragma unroll
    for (int n = 0; n < NCH; ++n) { e[n] = myrow[n]; m = fmaxf(m, e[n]); }
    float s = 0.f;
#pragma unroll
    for (int n = 0; n < NCH; ++n) { e[n] = __expf(e[n] - m); s += e[n]; }
    const float inv = 1.f / s;

    // ---- pack probs bf16 into same LDS (rows of ROW_U ushorts) ----
    // Safe overlay: wave-lockstep => all logit reads precede these writes;
    // compiler sees same-object alias and keeps LDS program order.
    unsigned* prow = (unsigned*)(smem + (size_t)lane * (ROW_U * 2));
#pragma unroll
    for (int i = 0; i < 34; ++i)
        prow[i] = bf16bits(e[2 * i] * inv) | (bf16bits(e[2 * i + 1] * inv) << 16);
    prow[34] = bf16bits(e[68] * inv);
#pragma unroll
    for (int i = 35; i < 48; ++i) prow[i] = 0;

    // ---- this wave's 12 A-fragments (4 M-tiles x 3 k-steps) ----
    const int w15   = lane & 15;
    const int kgrp  = (lane >> 4) * 8;
    const int crow4 = (lane >> 4) * 4;
    const unsigned short* pa = (const unsigned short*)smem;
    bfrag a[4][3];
#pragma unroll
    for (int mt = 0; mt < 4; ++mt)
#pragma unroll
        for (int ks = 0; ks < 3; ++ks)
            a[mt][ks] = *(const bfrag*)&pa[(size_t)(mt * 16 + w15) * ROW_U + ks * 32 + kgrp];

    // prob buffer dead after a-frag reads -> reuse as f32 stage (2 rows x 896)
    float* stage = (float*)smem;

    // ---- h loop: TWO image rows per iteration, double-buffered B ----
    const unsigned short* fb = Fh + (size_t)w15 * KP + kgrp;
    bfrag bcur[2][3], bnxt[2][3];
#pragma unroll
    for (int hh = 0; hh < 2; ++hh)
#pragma unroll
        for (int ks = 0; ks < 3; ++ks)
            bcur[hh][ks] = *(const bfrag*)(fb + (size_t)(hh * 16) * KP + ks * 32);

#pragma unroll 1
    for (int h2 = 0; h2 < CH / 2; ++h2) {
        const int h = 2 * h2;
        if (h2 + 1 < CH / 2) {
            const unsigned short* fn = fb + (size_t)((h + 2) * 16) * KP;
#pragma unroll
            for (int hh = 0; hh < 2; ++hh)
#pragma unroll
                for (int ks = 0; ks < 3; ++ks)
                    bnxt[hh][ks] = *(const bfrag*)(fn + (size_t)(hh * 16) * KP + ks * 32);
        }

        f32x4 acc[2][4];
#pragma unroll
        for (int hh = 0; hh < 2; ++hh)
#pragma unroll
            for (int mt = 0; mt < 4; ++mt)
                acc[hh][mt] = f32x4{0, 0, 0, 0};
#pragma unroll
        for (int hh = 0; hh < 2; ++hh)
#pragma unroll
            for (int mt = 0; mt < 4; ++mt)
#pragma unroll
                for (int ks = 0; ks < 3; ++ks)
                    acc[hh][mt] = __builtin_amdgcn_mfma_f32_16x16x32_bf16(
                        a[mt][ks], bcur[hh][ks], acc[hh][mt], 0, 0, 0);

        // transpose through wave-private LDS: stage[hh][cell_local*14 + w]
        if (w15 < CW) {
#pragma unroll
            for (int hh = 0; hh < 2; ++hh)
#pragma unroll
                for (int mt = 0; mt < 4; ++mt)
#pragma unroll
                    for (int j = 0; j < 4; ++j)
                        stage[hh * 896 + (mt * 16 + crow4 + j) * CW + w15] = acc[hh][mt][j];
        }

        // coalesced stores: per row, 896 floats = 224 float4 (4 masked insts)
#pragma unroll
        for (int hh = 0; hh < 2; ++hh) {
            float4* o4 = (float4*)(out + (size_t)(r * CH + h + hh) * IMG_W
                                       + (size_t)cb * CW);
            const float4* s4 = (const float4*)(stage + hh * 896);
#pragma unroll
            for (int i = 0; i < 4; ++i) {
                const int idx = i * 64 + lane;
                if (idx < 224) o4[idx] = s4[idx];
            }
        }

#pragma unroll
        for (int hh = 0; hh < 2; ++hh)
#pragma unroll
            for (int ks = 0; ks < 3; ++ks)
                bcur[hh][ks] = bnxt[hh][ks];
    }
}

extern "C" void kernel_launch(void* const* d_in, const int* in_sizes, int n_in,
                              void* d_out, int out_size, void* d_ws, size_t ws_size,
                              hipStream_t stream) {
    const float* logits = (const float*)d_in[0];   // (384,768,69) f32
    const float* font   = (const float*)d_in[1];   // (69,28,14)  f32
    float* out          = (float*)d_out;           // (10752,10752) f32
    unsigned short* Fh  = (unsigned short*)d_ws;   // (28,16,96) bf16 = 86KB

    font_prep<<<(CH * 16 * KP + 255) / 256, 256, 0, stream>>>(font, Fh);

    const int blocks = (ROWS * COLS) / 64;         // 4608 one-wave blocks
    diffrender_v7<<<blocks, 64, 0, stream>>>(logits, Fh, out);
}